// Round 3
// baseline (257.638 us; speedup 1.0000x reference)
//
#include <hip/hip_runtime.h>

#define BB 4
#define NLAM 96
#define HH 256
#define WW 256
#define HO 288
#define WO 288
#define NK 4
#define KS 15
#define PADK 7

#define ACC_N ((size_t)BB * NK * HO * WO)   // floats in one partial slice

// shift_accum LDS tile: contiguous rows, pitch 104 floats (26 quads) so that
// global_load_lds (wave-uniform dest + lane*16B) can stage it directly.
// Double-buffered: stage(lam+1) overlaps gather(lam).
#define SP 104
#define NQ 7                  // staging slots: 7*256 quads >= 65*26
#define TILE_Q (NQ * 256)     // 1792 quads = 28672 B
#define TILE_F (TILE_Q * 4)   // floats per buffer

typedef float f4a __attribute__((ext_vector_type(4)));
typedef float f8v __attribute__((ext_vector_type(8), aligned(16)));

// ---------------------------------------------------------------------------
// Kernel 0: per-(k,lam) shift params + offset min/max; also zeroes the 128 B
// zero-page used as the global_load_lds source for OOB quads.
// ---------------------------------------------------------------------------
__global__ __launch_bounds__(384) void params_k(const float* __restrict__ dx,
                                                const float* __restrict__ dy,
                                                float4* __restrict__ pw,
                                                int2* __restrict__ po,
                                                int4* __restrict__ gmm,
                                                float* __restrict__ zp) {
    __shared__ int sox[384], soy[384];
    const int i = threadIdx.x;
    if (i < 32) zp[i] = 0.0f;
    const float sx = -dx[i] - 16.0f;
    const float sy = -dy[i] - 16.0f;
    const float fx = floorf(sx), fy = floorf(sy);
    const int ox = (int)fx, oy = (int)fy;
    po[i] = make_int2(ox, oy);
    pw[i] = make_float4(1.0f - (sx - fx), sx - fx, 1.0f - (sy - fy), sy - fy);
    sox[i] = ox; soy[i] = oy;
    __syncthreads();
    if (i < 64) {
        int mnx = sox[i], mxx = mnx, mny = soy[i], mxy = mny;
        for (int j = i + 64; j < 384; j += 64) {
            mnx = min(mnx, sox[j]); mxx = max(mxx, sox[j]);
            mny = min(mny, soy[j]); mxy = max(mxy, soy[j]);
        }
        for (int m = 32; m; m >>= 1) {
            mnx = min(mnx, __shfl_xor(mnx, m, 64));
            mxx = max(mxx, __shfl_xor(mxx, m, 64));
            mny = min(mny, __shfl_xor(mny, m, 64));
            mxy = max(mxy, __shfl_xor(mxy, m, 64));
        }
        if (i == 0) *gmm = make_int4(mnx, mxx, mny, mxy);
    }
}

// ---------------------------------------------------------------------------
// Kernel 1: shift + accumulate over a lambda chunk; grid.z = BB * S.
// Double-buffered staging via global_load_lds with counted vmcnt (never 0 in
// the steady state): issue stage(lam+1) -> vmcnt(7) guarantees stage(lam)'s
// 7 oldest loads landed -> raw s_barrier (NO compiler vmcnt(0) drain) ->
// gather(lam) -> lgkmcnt(0) + raw barrier -> swap. Stage latency hides under
// the previous gather. All 7 slots always issued (beyond-Rq slots read the
// zero page) so the vmcnt immediate is constant.
// ---------------------------------------------------------------------------
#define HORW(P)                                                          \
    {                                                                    \
        f4a h0  = {vb0[P], vb0[(P)+1], vb0[(P)+2], vb0[(P)+3]};          \
        f4a h0s = {vb0[(P)+1], vb0[(P)+2], vb0[(P)+3], vb0[(P)+4]};      \
        f4a h1  = {vb1[P], vb1[(P)+1], vb1[(P)+2], vb1[(P)+3]};          \
        f4a h1s = {vb1[(P)+1], vb1[(P)+2], vb1[(P)+3], vb1[(P)+4]};      \
        a[k][0] += w.x * h0 + w.y * h0s;                                 \
        a[k][1] += w.x * h1 + w.y * h1s;                                 \
    }

#define STAGE_TO(DST, IB)                                                     \
    {                                                                         \
        _Pragma("unroll")                                                     \
        for (int s = 0; s < NQ; ++s) {                                        \
            const char* src = ((fm >> s) & 1) ? ((IB) + goffB[s]) : zpc;      \
            __builtin_amdgcn_global_load_lds(                                 \
                (const __attribute__((address_space(1))) unsigned int*)src,   \
                (__attribute__((address_space(3))) unsigned int*)             \
                    ((DST) + (s * 256 + ldsq0) * 4),                          \
                16, 0, 0);                                                    \
        }                                                                     \
    }

__global__ __launch_bounds__(256, 2) void shift_accum(
        const float* __restrict__ cube,
        const float4* __restrict__ pw,
        const int2* __restrict__ po,
        const int4* __restrict__ gmm,
        const float* __restrict__ zp,
        float* __restrict__ part,
        int S, int chunk) {
    __shared__ __align__(16) float tile[2 * TILE_F + 8];
    const int zc  = blockIdx.z;
    const int b   = zc / S;
    const int c   = zc - b * S;
    const int tx0 = blockIdx.x * 64;
    const int ty0 = blockIdx.y * 32;
    const int tx  = threadIdx.x, ty = threadIdx.y;
    const int x   = tx0 + tx * 4;
    const int y   = ty0 + ty * 2;
    const int tid = ty * 16 + tx;
    const float* __restrict__ cb = cube + (size_t)b * NLAM * HH * WW;

    const int4 mm = *gmm;   // uniform
    const int spanX = mm.y - mm.x;
    const int spanY = mm.w - mm.z;
    const bool lds_ok = (spanX <= 32) && (spanY <= 31);   // grid-uniform

    f4a a[NK][2];
#pragma unroll
    for (int k = 0; k < NK; ++k) { a[k][0] = (f4a)0.f; a[k][1] = (f4a)0.f; }

    const int l0 = min(NLAM, c * chunk);
    const int l1 = min(NLAM, l0 + chunk);

    if (lds_ok) {
        const int row0 = ty0 + mm.z;
        const int col0 = (tx0 + mm.x) & ~3;
        const int Rq   = (spanY + 34) * 26;       // staged quads (<= 1690)
        const int dx0  = tx0 - col0;
        const int tb0  = (ty * 2 - mm.z) * SP + tx * 4 + dx0;
        const int ldsq0 = tid & 192;              // wave-uniform quad base
        const char* zpc = (const char*)zp;
        (void)Rq;

        // ---- lambda-invariant staging precompute ----
        int goffB[NQ];     // byte offset into one cube slice (full quads only)
        int fm = 0;        // full-quad flags
        int pf = 0;        // partial-quad flags
#pragma unroll
        for (int s = 0; s < NQ; ++s) {
            const int q  = tid + s * 256;
            const bool inR = q < Rq;
            const int r  = q / 26;
            const int qi = q - r * 26;
            const int gy = row0 + r;
            const int gc = col0 + qi * 4;
            const bool rowOK = (unsigned)gy < (unsigned)HH;
            const bool fullQ = inR && rowOK && gc >= 0 && gc <= WW - 4;
            const bool partQ = inR && rowOK && !fullQ && (gc + 3 >= 0) && (gc < WW);
            goffB[s] = (gy * WW + gc) * 4;
            if (fullQ) fm |= 1 << s;
            if (partQ) pf |= 1 << s;
        }

        float* bufC = tile;            // compute buffer
        float* bufN = tile + TILE_F;   // staging (next) buffer

        // ---- prologue: stage first lambda ----
        {
            const char* ib0 = (const char*)(cb + l0 * (HH * WW));
            STAGE_TO(bufC, ib0)
        }

        for (int lam = l0; lam < l1; ++lam) {
            const char* __restrict__ ib = (const char*)(cb + lam * (HH * WW));
            const bool hasNext = (lam + 1 < l1);
            if (hasNext) {
                const char* ibn = (const char*)(cb + (lam + 1) * (HH * WW));
                STAGE_TO(bufN, ibn)
                // lam's 7 loads are the 7 oldest of <=14 outstanding.
                asm volatile("s_waitcnt vmcnt(7)" ::: "memory");
            } else {
                asm volatile("s_waitcnt vmcnt(0)" ::: "memory");
            }
            // ---- rare edge quads: patch valid lanes (loads have landed) ----
            if (pf) {
#pragma unroll
                for (int s = 0; s < NQ; ++s) {
                    if (pf & (1 << s)) {
                        const int q  = tid + s * 256;
                        const int r  = q / 26;
                        const int qi = q - r * 26;
                        const int gy = row0 + r;
                        const int gc = col0 + qi * 4;
                        const float* rp = (const float*)ib + gy * WW;
                        float* la = bufC + r * SP + qi * 4;
#pragma unroll
                        for (int e = 0; e < 4; ++e)
                            la[e] = ((unsigned)(gc + e) < (unsigned)WW)
                                        ? rp[gc + e] : 0.0f;
                    }
                }
                asm volatile("s_waitcnt lgkmcnt(0)" ::: "memory");
            }
            __builtin_amdgcn_s_barrier();
            __builtin_amdgcn_sched_barrier(0);
            // ---- gather 4 k's: aligned f8 rows, vertical blend, uniform
            //      phase switch for the horizontal window ----
#pragma unroll
            for (int k = 0; k < NK; ++k) {
                const int2 o = po[k * NLAM + lam];     // uniform scalar loads
                const float4 w = pw[k * NLAM + lam];
                const int bidx = tb0 + o.y * SP + o.x;
                const int p = __builtin_amdgcn_readfirstlane(bidx & 3);
                const float* ta = bufC + (bidx & ~3);
                const f8v R0 = *(const f8v*)ta;
                const f8v R1 = *(const f8v*)(ta + SP);
                const f8v R2 = *(const f8v*)(ta + 2 * SP);
                const f8v vb0 = w.z * R0 + w.w * R1;   // R0..R2 die here
                const f8v vb1 = w.z * R1 + w.w * R2;
                switch (p) {
                    case 0:  HORW(0); break;
                    case 1:  HORW(1); break;
                    case 2:  HORW(2); break;
                    default: HORW(3); break;
                }
            }
            if (hasNext) {
                // all this wave's ds_reads done -> after barrier, buffer swap
                // is safe against next iteration's global_load_lds overwrite.
                asm volatile("s_waitcnt lgkmcnt(0)" ::: "memory");
                __builtin_amdgcn_s_barrier();
                __builtin_amdgcn_sched_barrier(0);
            }
            float* t = bufC; bufC = bufN; bufN = t;
        }
    } else {
        // fallback: global clamped gather (correctness path, ~never taken)
        for (int lam = l0; lam < l1; ++lam) {
            const float* __restrict__ img = cb + lam * (HH * WW);
#pragma unroll
            for (int k = 0; k < NK; ++k) {
                const int i_ = k * NLAM + lam;
                const int2 o = po[i_]; const float4 w = pw[i_];
#pragma unroll
                for (int j = 0; j < 2; ++j) {
                    const int iy = y + j + o.y;
                    const int ix = x + o.x;
                    const int cy0 = min(max(iy, 0), HH - 1);
                    const int cy1 = min(max(iy + 1, 0), HH - 1);
                    const float my0 = ((unsigned)iy       < (unsigned)HH) ? w.z : 0.0f;
                    const float my1 = ((unsigned)(iy + 1) < (unsigned)HH) ? w.w : 0.0f;
                    const float* r0p = img + cy0 * WW;
                    const float* r1p = img + cy1 * WW;
                    float rb[5];
#pragma unroll
                    for (int cc = 0; cc < 5; ++cc) {
                        const int cx = min(max(ix + cc, 0), WW - 1);
                        const float m = ((unsigned)(ix + cc) < (unsigned)WW) ? 1.0f : 0.0f;
                        rb[cc] = m * (my0 * r0p[cx] + my1 * r1p[cx]);
                    }
                    f4a d;
                    d.x = w.x * rb[0] + w.y * rb[1];
                    d.y = w.x * rb[1] + w.y * rb[2];
                    d.z = w.x * rb[2] + w.y * rb[3];
                    d.w = w.x * rb[3] + w.y * rb[4];
                    a[k][j] += d;
                }
            }
        }
    }

    if (x < WO) {
        const size_t hw = (size_t)HO * WO;
        float* pa = part + (size_t)c * ACC_N + ((size_t)(b * NK) * HO + y) * WO + x;
#pragma unroll
        for (int k = 0; k < NK; ++k) {
            *(f4a*)(pa + (size_t)k * hw)      = a[k][0];
            *(f4a*)(pa + (size_t)k * hw + WO) = a[k][1];
        }
    }
}

// ---------------------------------------------------------------------------
// Kernel 2: 15x15 PSF correlation, zero-padded "same", summing S partials.
// Tile 96x16 outputs, block (24,8)=192 thr, 4x2 outputs/thread.
// Staging origin aligned to 16 B (bx*96-8) -> global_load_dwordx4 for all S
// slices; per-element mask; conv rows read as 5 aligned b128 with a
// compile-time +1 window shift.
// ---------------------------------------------------------------------------
#define CPX 112
#define CROWS 30
#define CTILE_N (CROWS * CPX)   // 3360
#define NQC 5

template <int S>
__global__ __launch_bounds__(192) void conv_psf(const float* __restrict__ part,
                                                const float* __restrict__ psf,
                                                float* __restrict__ out) {
    __shared__ __align__(16) float tilec[CTILE_N + 16];
    __shared__ __align__(16) float spsf[KS][16];
    const int bk  = blockIdx.z;               // b*4 + k
    const int gx0 = blockIdx.x * 96 - 8;      // aligned staging origin
    const int gy0 = blockIdx.y * 16 - PADK;
    const float* __restrict__ ap = part + (size_t)bk * HO * WO;

    const int tid = threadIdx.y * 24 + threadIdx.x;   // 0..191
    for (int i = tid; i < KS * 16; i += 192) {
        const int r = i >> 4, cc2 = i & 15;
        spsf[r][cc2] = (cc2 < KS) ? psf[r * KS + cc2] : 0.0f;
    }

    // staging precompute: all quads 16B-aligned
    int goffB[NQC], laddr[NQC];
    f4a cmask[NQC];
#pragma unroll
    for (int s = 0; s < NQC; ++s) {
        const int q  = tid + s * 192;
        const bool inR = q < CROWS * 28;
        const int r  = q / 28;
        const int qi = q - r * 28;
        const int gy = gy0 + r;
        const int gx = gx0 + qi * 4;
        const bool rowOK = (unsigned)gy < (unsigned)HO;
        const int gyc = min(max(gy, 0), HO - 1);
        goffB[s] = (gyc * WO + gx) * 4;           // may be slightly OOB: padded ws
        laddr[s] = inR ? (r * CPX + qi * 4) : CTILE_N;
        f4a m;
#pragma unroll
        for (int e = 0; e < 4; ++e)
            m[e] = (inR && rowOK && (unsigned)(gx + e) < (unsigned)WO) ? 1.0f : 0.0f;
        cmask[s] = m;
    }

#pragma unroll
    for (int s = 0; s < NQC; ++s) {
        const char* base = (const char*)ap + goffB[s];
        f4a acc = (f4a)0.f;
#pragma unroll
        for (int cc = 0; cc < S; ++cc)
            acc += *(const f4a*)(base + (size_t)cc * (ACC_N * 4));
        acc *= cmask[s];
        *(f4a*)(tilec + laddr[s]) = acc;
    }
    __syncthreads();

    const int x0 = threadIdx.x * 4;   // 0..92
    const int y0 = threadIdx.y * 2;   // 0..14
    f4a o0 = (f4a)0.f, o1 = (f4a)0.f;
    f4a prev0, prev1, prev2, prev3;

#pragma unroll
    for (int rr = 0; rr < 16; ++rr) {
        const float* rp = &tilec[(y0 + rr) * CPX + x0];
        float row[20];
#pragma unroll
        for (int q = 0; q < 5; ++q) {
            f4a v = *(const f4a*)(rp + 4 * q);
            row[4 * q]     = v.x; row[4 * q + 1] = v.y;
            row[4 * q + 2] = v.z; row[4 * q + 3] = v.w;
        }

        f4a c0, c1, c2, c3;
        if (rr < 15) {
            c0 = *(const f4a*)&spsf[rr][0];
            c1 = *(const f4a*)&spsf[rr][4];
            c2 = *(const f4a*)&spsf[rr][8];
            c3 = *(const f4a*)&spsf[rr][12];
        }
        if (rr < 15) {   // j=0: ky=rr, weights cur
#pragma unroll
            for (int kx = 0; kx < KS; ++kx) {
                const float wv = (kx < 4) ? c0[kx] : (kx < 8) ? c1[kx - 4]
                               : (kx < 12) ? c2[kx - 8] : c3[kx - 12];
                f4a rv = {row[kx + 1], row[kx + 2], row[kx + 3], row[kx + 4]};
                o0 += wv * rv;
            }
        }
        if (rr >= 1) {   // j=1: ky=rr-1, weights prev
#pragma unroll
            for (int kx = 0; kx < KS; ++kx) {
                const float wv = (kx < 4) ? prev0[kx] : (kx < 8) ? prev1[kx - 4]
                               : (kx < 12) ? prev2[kx - 8] : prev3[kx - 12];
                f4a rv = {row[kx + 1], row[kx + 2], row[kx + 3], row[kx + 4]};
                o1 += wv * rv;
            }
        }
        prev0 = c0; prev1 = c1; prev2 = c2; prev3 = c3;
    }

    const int xo = blockIdx.x * 96 + x0;
    const int yo = blockIdx.y * 16 + y0;
    float* op = out + ((size_t)bk * HO + yo) * WO + xo;
    *(f4a*)op        = o0;
    *(f4a*)(op + WO) = o1;
}

// ---------------------------------------------------------------------------
extern "C" void kernel_launch(void* const* d_in, const int* in_sizes, int n_in,
                              void* d_out, int out_size, void* d_ws, size_t ws_size,
                              hipStream_t stream) {
    const float* cube = (const float*)d_in[0];
    const float* dx   = (const float*)d_in[1];
    const float* dy   = (const float*)d_in[2];
    const float* psf  = (const float*)d_in[3];
    float* out = (float*)d_out;

    const size_t ACCB   = ACC_N * sizeof(float);
    const size_t tables = 384 * sizeof(float4) + 384 * sizeof(int2) + sizeof(int4);

    int S = 1;
    for (int cand : {12, 8, 6, 4, 3, 2}) {
        if (ws_size >= 128 + (size_t)cand * ACCB + tables + 4096) { S = cand; break; }
    }
    const int chunk = (NLAM + S - 1) / S;

    float* zp   = (float*)d_ws;                      // 128 B zero page
    float* part = (float*)((char*)d_ws + 128);       // 32 B of zp double as front pad
    char*  tb   = (char*)part + (size_t)S * ACCB;
    float4* pw  = (float4*)tb;
    int2*   po  = (int2*)(tb + 384 * sizeof(float4));
    int4*   gmm = (int4*)(tb + 384 * sizeof(float4) + 384 * sizeof(int2));

    params_k<<<1, 384, 0, stream>>>(dx, dy, pw, po, gmm, zp);

    dim3 b1(16, 16);
    dim3 g1((WO + 63) / 64, HO / 32, BB * S);
    shift_accum<<<g1, b1, 0, stream>>>(cube, pw, po, gmm, zp, part, S, chunk);

    dim3 b2(24, 8);
    dim3 g2(WO / 96, HO / 16, BB * NK);
    switch (S) {
        case 12: conv_psf<12><<<g2, b2, 0, stream>>>(part, psf, out); break;
        case 8:  conv_psf<8><<<g2, b2, 0, stream>>>(part, psf, out); break;
        case 6:  conv_psf<6><<<g2, b2, 0, stream>>>(part, psf, out); break;
        case 4:  conv_psf<4><<<g2, b2, 0, stream>>>(part, psf, out); break;
        case 3:  conv_psf<3><<<g2, b2, 0, stream>>>(part, psf, out); break;
        case 2:  conv_psf<2><<<g2, b2, 0, stream>>>(part, psf, out); break;
        default: conv_psf<1><<<g2, b2, 0, stream>>>(part, psf, out); break;
    }
}

// Round 5
// 206.076 us; speedup vs baseline: 1.2502x; 1.2502x over previous
//
#include <hip/hip_runtime.h>

#define BB 4
#define NLAM 96
#define HH 256
#define WW 256
#define HO 288
#define WO 288
#define NK 4
#define KS 15
#define PADK 7

#define ACC_N ((size_t)BB * NK * HO * WO)   // floats in one partial slice

// shift_accum LDS tile: contiguous rows, pitch 104 floats (26 quads) so that
// global_load_lds (wave-uniform dest + lane*16B) can stage it directly.
#define SP 104
#define NQ 7                  // staging slots: 7*256 quads >= 65*26
#define TILE_Q (NQ * 256)     // 1792 quads = 28672 B

typedef float f4a __attribute__((ext_vector_type(4)));
typedef float f8v __attribute__((ext_vector_type(8), aligned(16)));

// ---------------------------------------------------------------------------
// Kernel 0: per-(k,lam) shift params + offset min/max; also zeroes the 128 B
// zero-page used as the global_load_lds source for OOB quads.
// ---------------------------------------------------------------------------
__global__ __launch_bounds__(384) void params_k(const float* __restrict__ dx,
                                                const float* __restrict__ dy,
                                                float4* __restrict__ pw,
                                                int2* __restrict__ po,
                                                int4* __restrict__ gmm,
                                                float* __restrict__ zp) {
    __shared__ int sox[384], soy[384];
    const int i = threadIdx.x;
    if (i < 32) zp[i] = 0.0f;
    const float sx = -dx[i] - 16.0f;
    const float sy = -dy[i] - 16.0f;
    const float fx = floorf(sx), fy = floorf(sy);
    const int ox = (int)fx, oy = (int)fy;
    po[i] = make_int2(ox, oy);
    pw[i] = make_float4(1.0f - (sx - fx), sx - fx, 1.0f - (sy - fy), sy - fy);
    sox[i] = ox; soy[i] = oy;
    __syncthreads();
    if (i < 64) {
        int mnx = sox[i], mxx = mnx, mny = soy[i], mxy = mny;
        for (int j = i + 64; j < 384; j += 64) {
            mnx = min(mnx, sox[j]); mxx = max(mxx, sox[j]);
            mny = min(mny, soy[j]); mxy = max(mxy, soy[j]);
        }
        for (int m = 32; m; m >>= 1) {
            mnx = min(mnx, __shfl_xor(mnx, m, 64));
            mxx = max(mxx, __shfl_xor(mxx, m, 64));
            mny = min(mny, __shfl_xor(mny, m, 64));
            mxy = max(mxy, __shfl_xor(mxy, m, 64));
        }
        if (i == 0) *gmm = make_int4(mnx, mxx, mny, mxy);
    }
}

// ---------------------------------------------------------------------------
// Kernel 1: shift + accumulate over a lambda chunk; grid.z = BB * S.
// Round-2 structure (single buffer): measured 73 us. Double-buffering (r3)
// regressed to 110 us -- 58 KB LDS halved resident blocks/CU; inter-block
// TLP was worth more than intra-block overlap.
// ---------------------------------------------------------------------------
#define HORW(P)                                                          \
    {                                                                    \
        f4a h0  = {vb0[P], vb0[(P)+1], vb0[(P)+2], vb0[(P)+3]};          \
        f4a h0s = {vb0[(P)+1], vb0[(P)+2], vb0[(P)+3], vb0[(P)+4]};      \
        f4a h1  = {vb1[P], vb1[(P)+1], vb1[(P)+2], vb1[(P)+3]};          \
        f4a h1s = {vb1[(P)+1], vb1[(P)+2], vb1[(P)+3], vb1[(P)+4]};      \
        a[k][0] += w.x * h0 + w.y * h0s;                                 \
        a[k][1] += w.x * h1 + w.y * h1s;                                 \
    }

__global__ __launch_bounds__(256, 2) void shift_accum(
        const float* __restrict__ cube,
        const float4* __restrict__ pw,
        const int2* __restrict__ po,
        const int4* __restrict__ gmm,
        const float* __restrict__ zp,
        float* __restrict__ part,
        int S, int chunk) {
    __shared__ __align__(16) float tile[TILE_Q * 4 + 8];
    const int zc  = blockIdx.z;
    const int b   = zc / S;
    const int c   = zc - b * S;
    const int tx0 = blockIdx.x * 64;
    const int ty0 = blockIdx.y * 32;
    const int tx  = threadIdx.x, ty = threadIdx.y;
    const int x   = tx0 + tx * 4;
    const int y   = ty0 + ty * 2;
    const int tid = ty * 16 + tx;
    const float* __restrict__ cb = cube + (size_t)b * NLAM * HH * WW;

    const int4 mm = *gmm;   // uniform
    const int spanX = mm.y - mm.x;
    const int spanY = mm.w - mm.z;
    const bool lds_ok = (spanX <= 32) && (spanY <= 31);   // grid-uniform

    f4a a[NK][2];
#pragma unroll
    for (int k = 0; k < NK; ++k) { a[k][0] = (f4a)0.f; a[k][1] = (f4a)0.f; }

    const int l0 = min(NLAM, c * chunk);
    const int l1 = min(NLAM, l0 + chunk);

    if (lds_ok) {
        const int row0 = ty0 + mm.z;
        const int col0 = (tx0 + mm.x) & ~3;
        const int R    = spanY + 34;              // staged rows, <= 65
        const int Rq   = R * 26;                  // staged quads
        const int dx0  = tx0 - col0;
        const int tb0  = (ty * 2 - mm.z) * SP + tx * 4 + dx0;
        const int ldsq0 = tid & 192;              // wave-uniform quad base
        const char* zpc = (const char*)zp;

        // ---- lambda-invariant staging precompute ----
        int goffB[NQ];     // byte offset into one cube slice (full quads only)
        int fm = 0;        // full-quad flags
        int pf = 0;        // partial-quad flags
#pragma unroll
        for (int s = 0; s < NQ; ++s) {
            const int q  = tid + s * 256;
            const bool inR = q < Rq;
            const int r  = q / 26;
            const int qi = q - r * 26;
            const int gy = row0 + r;
            const int gc = col0 + qi * 4;
            const bool rowOK = (unsigned)gy < (unsigned)HH;
            const bool fullQ = inR && rowOK && gc >= 0 && gc <= WW - 4;
            const bool partQ = inR && rowOK && !fullQ && (gc + 3 >= 0) && (gc < WW);
            goffB[s] = (gy * WW + gc) * 4;
            if (fullQ) fm |= 1 << s;
            if (partQ) pf |= 1 << s;
        }

        for (int lam = l0; lam < l1; ++lam) {
            const char* __restrict__ ib = (const char*)(cb + lam * (HH * WW));
            // ---- stage: direct global->LDS, zero-page for non-full quads ----
#pragma unroll
            for (int s = 0; s < NQ; ++s) {
                if (s * 256 < Rq) {   // block-uniform slot skip
                    const char* src = ((fm >> s) & 1) ? (ib + goffB[s]) : zpc;
                    __builtin_amdgcn_global_load_lds(
                        (const __attribute__((address_space(1))) unsigned int*)src,
                        (__attribute__((address_space(3))) unsigned int*)
                            (tile + (s * 256 + ldsq0) * 4),
                        16, 0, 0);
                }
            }
            // ---- rare edge quads: patch valid lanes after loads land ----
            if (pf) {
                asm volatile("s_waitcnt vmcnt(0)" ::: "memory");
#pragma unroll
                for (int s = 0; s < NQ; ++s) {
                    if (pf & (1 << s)) {
                        const int q  = tid + s * 256;
                        const int r  = q / 26;
                        const int qi = q - r * 26;
                        const int gy = row0 + r;
                        const int gc = col0 + qi * 4;
                        const float* rp = (const float*)ib + gy * WW;
                        const int la = r * SP + qi * 4;
#pragma unroll
                        for (int e = 0; e < 4; ++e)
                            tile[la + e] = ((unsigned)(gc + e) < (unsigned)WW)
                                               ? rp[gc + e] : 0.0f;
                    }
                }
            }
            __syncthreads();
            // ---- gather 4 k's: aligned f8 rows, vertical blend, uniform
            //      phase switch for the horizontal window ----
#pragma unroll
            for (int k = 0; k < NK; ++k) {
                const int2 o = po[k * NLAM + lam];     // uniform scalar loads
                const float4 w = pw[k * NLAM + lam];
                const int bidx = tb0 + o.y * SP + o.x;
                const int p = __builtin_amdgcn_readfirstlane(bidx & 3);
                const float* ta = tile + (bidx & ~3);
                const f8v R0 = *(const f8v*)ta;
                const f8v R1 = *(const f8v*)(ta + SP);
                const f8v R2 = *(const f8v*)(ta + 2 * SP);
                const f8v vb0 = w.z * R0 + w.w * R1;   // R0..R2 die here
                const f8v vb1 = w.z * R1 + w.w * R2;
                switch (p) {
                    case 0:  HORW(0); break;
                    case 1:  HORW(1); break;
                    case 2:  HORW(2); break;
                    default: HORW(3); break;
                }
            }
            __syncthreads();
        }
    } else {
        // fallback: global clamped gather (correctness path, ~never taken)
        for (int lam = l0; lam < l1; ++lam) {
            const float* __restrict__ img = cb + lam * (HH * WW);
#pragma unroll
            for (int k = 0; k < NK; ++k) {
                const int i_ = k * NLAM + lam;
                const int2 o = po[i_]; const float4 w = pw[i_];
#pragma unroll
                for (int j = 0; j < 2; ++j) {
                    const int iy = y + j + o.y;
                    const int ix = x + o.x;
                    const int cy0 = min(max(iy, 0), HH - 1);
                    const int cy1 = min(max(iy + 1, 0), HH - 1);
                    const float my0 = ((unsigned)iy       < (unsigned)HH) ? w.z : 0.0f;
                    const float my1 = ((unsigned)(iy + 1) < (unsigned)HH) ? w.w : 0.0f;
                    const float* r0p = img + cy0 * WW;
                    const float* r1p = img + cy1 * WW;
                    float rb[5];
#pragma unroll
                    for (int cc = 0; cc < 5; ++cc) {
                        const int cx = min(max(ix + cc, 0), WW - 1);
                        const float m = ((unsigned)(ix + cc) < (unsigned)WW) ? 1.0f : 0.0f;
                        rb[cc] = m * (my0 * r0p[cx] + my1 * r1p[cx]);
                    }
                    f4a d;
                    d.x = w.x * rb[0] + w.y * rb[1];
                    d.y = w.x * rb[1] + w.y * rb[2];
                    d.z = w.x * rb[2] + w.y * rb[3];
                    d.w = w.x * rb[3] + w.y * rb[4];
                    a[k][j] += d;
                }
            }
        }
    }

    if (x < WO) {
        const size_t hw = (size_t)HO * WO;
        float* pa = part + (size_t)c * ACC_N + ((size_t)(b * NK) * HO + y) * WO + x;
#pragma unroll
        for (int k = 0; k < NK; ++k) {
            *(f4a*)(pa + (size_t)k * hw)      = a[k][0];
            *(f4a*)(pa + (size_t)k * hw + WO) = a[k][1];
        }
    }
}

// ---------------------------------------------------------------------------
// Kernel 1.5: sum the S partial slices into slice 0. Fully coalesced f4
// streams, 1296 blocks x 256 thr (exactly one quad per thread) -> BW-bound.
// This removes the 12-stream scattered gather from conv_psf's staging, which
// was latency-exposed at only ~10 waves/CU of TLP.
// ---------------------------------------------------------------------------
template <int S>
__global__ __launch_bounds__(256) void reduce_k(float* __restrict__ part) {
    const size_t i = ((size_t)blockIdx.x * 256 + threadIdx.x) * 4;
    f4a acc = *(const f4a*)(part + i);
#pragma unroll
    for (int cc = 1; cc < S; ++cc)
        acc += *(const f4a*)(part + (size_t)cc * ACC_N + i);
    *(f4a*)(part + i) = acc;
}

// ---------------------------------------------------------------------------
// Kernel 2: 15x15 PSF correlation, zero-padded "same", on the reduced slice.
// Tile 96x16 outputs, block (24,8)=192 thr, 4x2 outputs/thread.
// Staging origin aligned to 16 B (bx*96-8) -> global_load_dwordx4; conv rows
// read as 5 aligned b128 with a compile-time +1 window shift.
// ---------------------------------------------------------------------------
#define CPX 112
#define CROWS 30
#define CTILE_N (CROWS * CPX)   // 3360
#define NQC 5

__global__ __launch_bounds__(192) void conv_psf(const float* __restrict__ part,
                                                const float* __restrict__ psf,
                                                float* __restrict__ out) {
    __shared__ __align__(16) float tilec[CTILE_N + 16];
    __shared__ __align__(16) float spsf[KS][16];
    const int bk  = blockIdx.z;               // b*4 + k
    const int gx0 = blockIdx.x * 96 - 8;      // aligned staging origin
    const int gy0 = blockIdx.y * 16 - PADK;
    const float* __restrict__ ap = part + (size_t)bk * HO * WO;

    const int tid = threadIdx.y * 24 + threadIdx.x;   // 0..191
    for (int i = tid; i < KS * 16; i += 192) {
        const int r = i >> 4, cc2 = i & 15;
        spsf[r][cc2] = (cc2 < KS) ? psf[r * KS + cc2] : 0.0f;
    }

    // staging precompute: all quads 16B-aligned
#pragma unroll
    for (int s = 0; s < NQC; ++s) {
        const int q  = tid + s * 192;
        const bool inR = q < CROWS * 28;
        const int r  = q / 28;
        const int qi = q - r * 28;
        const int gy = gy0 + r;
        const int gx = gx0 + qi * 4;
        const bool rowOK = (unsigned)gy < (unsigned)HO;
        const int gyc = min(max(gy, 0), HO - 1);
        const int goffB = (gyc * WO + gx) * 4;    // may be slightly OOB: padded ws
        const int laddr = inR ? (r * CPX + qi * 4) : CTILE_N;
        f4a m;
#pragma unroll
        for (int e = 0; e < 4; ++e)
            m[e] = (inR && rowOK && (unsigned)(gx + e) < (unsigned)WO) ? 1.0f : 0.0f;
        f4a v = *(const f4a*)((const char*)ap + goffB);
        *(f4a*)(tilec + laddr) = v * m;
    }
    __syncthreads();

    const int x0 = threadIdx.x * 4;   // 0..92
    const int y0 = threadIdx.y * 2;   // 0..14
    f4a o0 = (f4a)0.f, o1 = (f4a)0.f;
    f4a prev0, prev1, prev2, prev3;

#pragma unroll
    for (int rr = 0; rr < 16; ++rr) {
        const float* rp = &tilec[(y0 + rr) * CPX + x0];
        float row[20];
#pragma unroll
        for (int q = 0; q < 5; ++q) {
            f4a v = *(const f4a*)(rp + 4 * q);
            row[4 * q]     = v.x; row[4 * q + 1] = v.y;
            row[4 * q + 2] = v.z; row[4 * q + 3] = v.w;
        }

        f4a c0, c1, c2, c3;
        if (rr < 15) {
            c0 = *(const f4a*)&spsf[rr][0];
            c1 = *(const f4a*)&spsf[rr][4];
            c2 = *(const f4a*)&spsf[rr][8];
            c3 = *(const f4a*)&spsf[rr][12];
        }
        if (rr < 15) {   // j=0: ky=rr, weights cur
#pragma unroll
            for (int kx = 0; kx < KS; ++kx) {
                const float wv = (kx < 4) ? c0[kx] : (kx < 8) ? c1[kx - 4]
                               : (kx < 12) ? c2[kx - 8] : c3[kx - 12];
                f4a rv = {row[kx + 1], row[kx + 2], row[kx + 3], row[kx + 4]};
                o0 += wv * rv;
            }
        }
        if (rr >= 1) {   // j=1: ky=rr-1, weights prev
#pragma unroll
            for (int kx = 0; kx < KS; ++kx) {
                const float wv = (kx < 4) ? prev0[kx] : (kx < 8) ? prev1[kx - 4]
                               : (kx < 12) ? prev2[kx - 8] : prev3[kx - 12];
                f4a rv = {row[kx + 1], row[kx + 2], row[kx + 3], row[kx + 4]};
                o1 += wv * rv;
            }
        }
        prev0 = c0; prev1 = c1; prev2 = c2; prev3 = c3;
    }

    const int xo = blockIdx.x * 96 + x0;
    const int yo = blockIdx.y * 16 + y0;
    float* op = out + ((size_t)bk * HO + yo) * WO + xo;
    *(f4a*)op        = o0;
    *(f4a*)(op + WO) = o1;
}

// ---------------------------------------------------------------------------
extern "C" void kernel_launch(void* const* d_in, const int* in_sizes, int n_in,
                              void* d_out, int out_size, void* d_ws, size_t ws_size,
                              hipStream_t stream) {
    const float* cube = (const float*)d_in[0];
    const float* dx   = (const float*)d_in[1];
    const float* dy   = (const float*)d_in[2];
    const float* psf  = (const float*)d_in[3];
    float* out = (float*)d_out;

    const size_t ACCB   = ACC_N * sizeof(float);
    const size_t tables = 384 * sizeof(float4) + 384 * sizeof(int2) + sizeof(int4);

    int S = 1;
    for (int cand : {12, 8, 6, 4, 3, 2}) {
        if (ws_size >= 128 + (size_t)cand * ACCB + tables + 4096) { S = cand; break; }
    }
    const int chunk = (NLAM + S - 1) / S;

    float* zp   = (float*)d_ws;                      // 128 B zero page
    float* part = (float*)((char*)d_ws + 128);       // 32 B of zp double as front pad
    char*  tb   = (char*)part + (size_t)S * ACCB;
    float4* pw  = (float4*)tb;
    int2*   po  = (int2*)(tb + 384 * sizeof(float4));
    int4*   gmm = (int4*)(tb + 384 * sizeof(float4) + 384 * sizeof(int2));

    params_k<<<1, 384, 0, stream>>>(dx, dy, pw, po, gmm, zp);

    dim3 b1(16, 16);
    dim3 g1((WO + 63) / 64, HO / 32, BB * S);
    shift_accum<<<g1, b1, 0, stream>>>(cube, pw, po, gmm, zp, part, S, chunk);

    const int rblocks = (int)(ACC_N / 4 / 256);      // 1296, exact
    switch (S) {
        case 12: reduce_k<12><<<rblocks, 256, 0, stream>>>(part); break;
        case 8:  reduce_k<8><<<rblocks, 256, 0, stream>>>(part); break;
        case 6:  reduce_k<6><<<rblocks, 256, 0, stream>>>(part); break;
        case 4:  reduce_k<4><<<rblocks, 256, 0, stream>>>(part); break;
        case 3:  reduce_k<3><<<rblocks, 256, 0, stream>>>(part); break;
        case 2:  reduce_k<2><<<rblocks, 256, 0, stream>>>(part); break;
        default: break;   // S==1: nothing to reduce
    }

    dim3 b2(24, 8);
    dim3 g2(WO / 96, HO / 16, BB * NK);
    conv_psf<<<g2, b2, 0, stream>>>(part, psf, out);
}